// Round 1
// baseline (545.896 us; speedup 1.0000x reference)
//
#include <hip/hip_runtime.h>
#include <cstddef>

// Vanilla tanh-RNN: B=4096, T=2048, I=4, H=20, then Linear(20 -> 4) on h_last.
//
// Parallelization: 32 lanes per batch element; lane j owns hidden unit j
// (lanes 20..31 are zero-padded dummies). h state lives in LDS (one 32-float
// row per element). All cross-lane traffic is intra-wave (wave = 2 elements),
// so NO barriers in the T-loop: the DS pipe processes a wave's LDS ops in
// program order, so the ds_write of step t is visible to the ds_reads of
// step t+1 issued by the same wave.
//
// Grid: 512 blocks x 256 threads = 2048 waves = 2 waves/SIMD on 256 CUs,
// giving 4 independent recurrence chains per SIMD to hide the per-step
// LDS round-trip + tanh latency.

constexpr int Tn  = 2048;
constexpr int Hn  = 20;
constexpr int EPB = 8;   // elements per 256-thread block

__device__ __forceinline__ float tanh_fast(float s) {
    // tanh(s) = 1 - 2/(exp(2s)+1); exp(2s) = exp2(s * 2*log2(e))
    // v_exp_f32 / v_rcp_f32 are ~1 ulp: plenty for the 1.79e-2 abs threshold.
    float e = __builtin_amdgcn_exp2f(s * 2.88539008177792681472f);
    float r = __builtin_amdgcn_rcpf(e + 1.0f);
    return __builtin_fmaf(-2.0f, r, 1.0f);
}

__global__ __launch_bounds__(256, 2) void rnn_fwd(
    const float* __restrict__ x,     // [B, T, 4]
    const float* __restrict__ h0,    // [B, 20]
    const float* __restrict__ W_ih,  // [20, 4]
    const float* __restrict__ W_hh,  // [20, 20]
    const float* __restrict__ b_ih,  // [20]
    const float* __restrict__ b_hh,  // [20]
    const float* __restrict__ fc_w,  // [4, 20]
    const float* __restrict__ fc_b,  // [4]
    float* __restrict__ out)         // [B, 4]
{
    __shared__ __align__(16) float hbuf[EPB][32];

    const int tid = threadIdx.x;
    const int g   = tid >> 5;        // element slot within block (0..7)
    const int j   = tid & 31;        // hidden-unit index (0..31, real < 20)
    const int b   = blockIdx.x * EPB + g;
    const bool rj = (j < Hn);

    // Per-lane weight row (zeros for padded lanes -> they compute tanh(0)=0).
    float Whh[Hn];
#pragma unroll
    for (int k = 0; k < Hn; ++k) Whh[k] = rj ? W_hh[j * Hn + k] : 0.0f;
    const float Wih0 = rj ? W_ih[j * 4 + 0] : 0.0f;
    const float Wih1 = rj ? W_ih[j * 4 + 1] : 0.0f;
    const float Wih2 = rj ? W_ih[j * 4 + 2] : 0.0f;
    const float Wih3 = rj ? W_ih[j * 4 + 3] : 0.0f;
    const float bias = rj ? (b_ih[j] + b_hh[j]) : 0.0f;

    hbuf[g][j] = rj ? h0[b * Hn + j] : 0.0f;

    const float4* __restrict__ xp = reinterpret_cast<const float4*>(x) + (size_t)b * Tn;

    auto step = [&](float4 xv) {
        // Broadcast read of this element's full h vector (5 x ds_read_b128,
        // all lanes of the group at the same address -> conflict-free).
        float4 p0 = *reinterpret_cast<const float4*>(&hbuf[g][0]);
        float4 p1 = *reinterpret_cast<const float4*>(&hbuf[g][4]);
        float4 p2 = *reinterpret_cast<const float4*>(&hbuf[g][8]);
        float4 p3 = *reinterpret_cast<const float4*>(&hbuf[g][12]);
        float4 p4 = *reinterpret_cast<const float4*>(&hbuf[g][16]);
        // 4 independent accumulator chains for ILP.
        float a0 = __builtin_fmaf(xv.x, Wih0, bias);
        float a1 = xv.y * Wih1;
        float a2 = xv.z * Wih2;
        float a3 = xv.w * Wih3;
        a0 = __builtin_fmaf(p0.x, Whh[0],  a0);
        a1 = __builtin_fmaf(p0.y, Whh[1],  a1);
        a2 = __builtin_fmaf(p0.z, Whh[2],  a2);
        a3 = __builtin_fmaf(p0.w, Whh[3],  a3);
        a0 = __builtin_fmaf(p1.x, Whh[4],  a0);
        a1 = __builtin_fmaf(p1.y, Whh[5],  a1);
        a2 = __builtin_fmaf(p1.z, Whh[6],  a2);
        a3 = __builtin_fmaf(p1.w, Whh[7],  a3);
        a0 = __builtin_fmaf(p2.x, Whh[8],  a0);
        a1 = __builtin_fmaf(p2.y, Whh[9],  a1);
        a2 = __builtin_fmaf(p2.z, Whh[10], a2);
        a3 = __builtin_fmaf(p2.w, Whh[11], a3);
        a0 = __builtin_fmaf(p3.x, Whh[12], a0);
        a1 = __builtin_fmaf(p3.y, Whh[13], a1);
        a2 = __builtin_fmaf(p3.z, Whh[14], a2);
        a3 = __builtin_fmaf(p3.w, Whh[15], a3);
        a0 = __builtin_fmaf(p4.x, Whh[16], a0);
        a1 = __builtin_fmaf(p4.y, Whh[17], a1);
        a2 = __builtin_fmaf(p4.z, Whh[18], a2);
        a3 = __builtin_fmaf(p4.w, Whh[19], a3);
        float s = (a0 + a1) + (a2 + a3);
        hbuf[g][j] = tanh_fast(s);
    };

    // x prefetched one 64B line (4 steps) ahead in registers: enough slack
    // (~4 step-chains) to cover L2/HBM latency without stalling the chain.
    float4 x0 = xp[0], x1 = xp[1], x2 = xp[2], x3 = xp[3];
#pragma unroll 1
    for (int t = 0; t < Tn; t += 4) {
        const int tp = (t + 4 <= Tn - 4) ? (t + 4) : (Tn - 4);  // clamp: last iter reloads tail (in-bounds)
        float4 n0 = xp[tp + 0];
        float4 n1 = xp[tp + 1];
        float4 n2 = xp[tp + 2];
        float4 n3 = xp[tp + 3];
        step(x0); step(x1); step(x2); step(x3);
        x0 = n0; x1 = n1; x2 = n2; x3 = n3;
    }

    // Epilogue: out[b][m] = fc_b[m] + sum_k h_last[k] * fc_w[m][k]
    if (j < 4) {
        float o = fc_b[j];
#pragma unroll
        for (int k = 0; k < Hn; ++k)
            o = __builtin_fmaf(hbuf[g][k], fc_w[j * Hn + k], o);
        out[b * 4 + j] = o;
    }
}

extern "C" void kernel_launch(void* const* d_in, const int* in_sizes, int n_in,
                              void* d_out, int out_size, void* d_ws, size_t ws_size,
                              hipStream_t stream) {
    const float* x    = (const float*)d_in[0];
    const float* h0   = (const float*)d_in[1];
    const float* W_ih = (const float*)d_in[2];
    const float* W_hh = (const float*)d_in[3];
    const float* b_ih = (const float*)d_in[4];
    const float* b_hh = (const float*)d_in[5];
    const float* fc_w = (const float*)d_in[6];
    const float* fc_b = (const float*)d_in[7];
    float* out = (float*)d_out;

    // 4096 elements / 8 per block = 512 blocks; 2048 waves = 2 waves/SIMD.
    rnn_fwd<<<dim3(512), dim3(256), 0, stream>>>(x, h0, W_ih, W_hh, b_ih, b_hh,
                                                 fc_w, fc_b, out);
}